// Round 1
// baseline (438.968 us; speedup 1.0000x reference)
//
#include <hip/hip_runtime.h>
#include <math.h>

#define NEMB 200000
#define DD   128
#define MM   200
#define KTOP 32
#define BB   1024
#define FEW  5
#define DM   256
#define DF   512
#define HH   512

__device__ __forceinline__ float sigf(float x) { return 1.0f / (1.0f + expf(-x)); }

// ---------------------------------------------------------------------------
// K1: neighbor encoder. One block per output (row, half). 2058 blocks.
// ---------------------------------------------------------------------------
__global__ __launch_bounds__(256) void neighbor_kernel(
    const int* __restrict__ query, const int* __restrict__ support,
    const int* __restrict__ q_l_conn, const int* __restrict__ q_r_conn,
    const int* __restrict__ s_l_conn, const int* __restrict__ s_r_conn,
    const float* __restrict__ emb,
    const float* __restrict__ gcn_W, const float* __restrict__ gcn_bias,
    const float* __restrict__ gcn_b, float* __restrict__ qn2)
{
    __shared__ float cent[128];
    __shared__ float sims[MM];
    __shared__ int   cids[MM];
    __shared__ int   selr[KTOP];
    __shared__ int   sele[KTOP];
    __shared__ float avg[256];
    __shared__ float red[256];
    __shared__ float cn_sh;
    __shared__ int   nsel;

    const int t   = threadIdx.x;
    const int blk = blockIdx.x;

    const int* conn; int eid, row_out, half;
    if (blk < BB)            { conn = q_l_conn + blk * MM * 2;              eid = query[blk * 2 + 0];             row_out = blk;            half = 0; }
    else if (blk < 2 * BB)   { int b = blk - BB;       conn = q_r_conn + b * MM * 2; eid = query[b * 2 + 1];     row_out = b;              half = 1; }
    else if (blk < 2 * BB + FEW) { int r = blk - 2 * BB;  conn = s_l_conn + r * MM * 2; eid = support[r * 2 + 0]; row_out = BB + r;         half = 0; }
    else                     { int r = blk - 2 * BB - FEW; conn = s_r_conn + r * MM * 2; eid = support[r * 2 + 1]; row_out = BB + r;        half = 1; }

    if (t < 128) cent[t] = emb[eid * DD + t];
    if (t < MM)  cids[t] = conn[t * 2 + 1];
    if (t == 0)  nsel = 0;
    __syncthreads();

    const int lane = t & 63;
    const int wave = t >> 6;
    if (wave == 0) {
        float c0 = cent[lane], c1 = cent[64 + lane];
        float s = c0 * c0 + c1 * c1;
        #pragma unroll
        for (int i = 32; i >= 1; i >>= 1) s += __shfl_xor(s, i, 64);
        if (lane == 0) cn_sh = sqrtf(s);
    }
    __syncthreads();

    const float cnv = cn_sh;
    const float c0 = cent[lane], c1 = cent[64 + lane];
    for (int jj = wave; jj < MM; jj += 4) {
        int rid = cids[jj];
        const float* er = emb + rid * DD;
        float e0 = er[lane], e1 = er[64 + lane];
        float num = c0 * e0 + c1 * e1;
        float sq  = e0 * e0 + e1 * e1;
        #pragma unroll
        for (int i = 32; i >= 1; i >>= 1) {
            num += __shfl_xor(num, i, 64);
            sq  += __shfl_xor(sq, i, 64);
        }
        if (lane == 0) sims[jj] = num / fmaxf(cnv * sqrtf(sq), 1e-8f);
    }
    __syncthreads();

    // top-K selection via rank; tie-break: lower index first (lax.top_k semantics)
    if (t < MM) {
        float st = sims[t];
        int cnt = 0;
        for (int j = 0; j < MM; ++j) {
            float sj = sims[j];
            cnt += (sj > st) || (sj == st && j < t);
        }
        if (cnt < KTOP) {
            int p = atomicAdd(&nsel, 1);
            selr[p] = conn[t * 2 + 0];
            sele[p] = cids[t];
        }
    }
    __syncthreads();

    // mean over selected K of [rel; ent]  (256 dims, one per thread)
    {
        float acc = 0.0f;
        const int dloc = t & 127;
        const bool is_ent = (t >= 128);
        for (int s = 0; s < KTOP; ++s) {
            int rid = is_ent ? sele[s] : selr[s];
            acc += emb[rid * DD + dloc];
        }
        avg[t] = acc * (1.0f / KTOP);
    }
    __syncthreads();

    // out[d] = tanh( gcn_W[d,:] . avg + gcn_bias[d] + gcn_b[d] )
    {
        const int d   = t & 127;
        const int c0i = (t >> 7) * 128;
        float acc = 0.0f;
        const float* wrow = gcn_W + d * 256 + c0i;
        #pragma unroll 4
        for (int c = 0; c < 128; ++c) acc += wrow[c] * avg[c0i + c];
        red[t] = acc;
    }
    __syncthreads();
    if (t < 128) {
        float o = red[t] + red[t + 128] + gcn_bias[t] + gcn_b[t];
        qn2[row_out * 256 + half * 128 + t] = tanhf(o);
    }
}

// ---------------------------------------------------------------------------
// Generic fp32 GEMM: C[M,N] = A[M,K] @ W[N',K]^T (+bias)(+add)(relu)
// GMAP remaps output col n -> W row ((n>>8)<<9)|(n&255)  (gate compaction)
// Block tile 64x64, K-tile 16, 256 threads, 4x4 microtile.
// ---------------------------------------------------------------------------
template <bool RELU, bool HAS_ADD, bool GMAP>
__global__ __launch_bounds__(256) void gemm_nt(
    const float* __restrict__ A, const float* __restrict__ W,
    const float* __restrict__ bias, const float* __restrict__ add,
    float* __restrict__ C, int M_, int N_, int K_)
{
    __shared__ float As[16][68];
    __shared__ float Ws[16][68];
    const int t  = threadIdx.x;
    const int bm = blockIdx.y * 64, bn = blockIdx.x * 64;
    const int tx = t & 15, ty = t >> 4;
    const int lrow = t >> 2, lk4 = (t & 3) * 4;

    int wrow = bn + lrow;
    if (GMAP) wrow = ((wrow >> 8) << 9) | (wrow & 255);
    const float* Ap = A + (bm + lrow) * K_ + lk4;
    const float* Wp = W + wrow * K_ + lk4;

    float acc[4][4] = {};
    for (int k0 = 0; k0 < K_; k0 += 16) {
        float4 av = *(const float4*)(Ap + k0);
        float4 wv = *(const float4*)(Wp + k0);
        __syncthreads();
        As[lk4 + 0][lrow] = av.x; As[lk4 + 1][lrow] = av.y;
        As[lk4 + 2][lrow] = av.z; As[lk4 + 3][lrow] = av.w;
        Ws[lk4 + 0][lrow] = wv.x; Ws[lk4 + 1][lrow] = wv.y;
        Ws[lk4 + 2][lrow] = wv.z; Ws[lk4 + 3][lrow] = wv.w;
        __syncthreads();
        #pragma unroll
        for (int kk = 0; kk < 16; ++kk) {
            float4 a = *(const float4*)&As[kk][ty * 4];
            float4 b = *(const float4*)&Ws[kk][tx * 4];
            acc[0][0] += a.x * b.x; acc[0][1] += a.x * b.y; acc[0][2] += a.x * b.z; acc[0][3] += a.x * b.w;
            acc[1][0] += a.y * b.x; acc[1][1] += a.y * b.y; acc[1][2] += a.y * b.z; acc[1][3] += a.y * b.w;
            acc[2][0] += a.z * b.x; acc[2][1] += a.z * b.y; acc[2][2] += a.z * b.z; acc[2][3] += a.z * b.w;
            acc[3][0] += a.w * b.x; acc[3][1] += a.w * b.y; acc[3][2] += a.w * b.z; acc[3][3] += a.w * b.w;
        }
    }

    const int n0 = bn + tx * 4;
    float4 bv = make_float4(0.f, 0.f, 0.f, 0.f);
    if (bias) {
        int nb = GMAP ? (((n0 >> 8) << 9) | (n0 & 255)) : n0;
        bv = *(const float4*)(bias + nb);
    }
    #pragma unroll
    for (int i = 0; i < 4; ++i) {
        int m = bm + ty * 4 + i;
        float4 v = make_float4(acc[i][0] + bv.x, acc[i][1] + bv.y,
                               acc[i][2] + bv.z, acc[i][3] + bv.w);
        if (HAS_ADD) {
            float4 ad = *(const float4*)(add + m * N_ + n0);
            v.x += ad.x; v.y += ad.y; v.z += ad.z; v.w += ad.w;
        }
        if (RELU) {
            v.x = fmaxf(v.x, 0.f); v.y = fmaxf(v.y, 0.f);
            v.z = fmaxf(v.z, 0.f); v.w = fmaxf(v.w, 0.f);
        }
        *(float4*)(C + m * N_ + n0) = v;
    }
}

// ---------------------------------------------------------------------------
// LayerNorm per row (256 dims)
// ---------------------------------------------------------------------------
__global__ __launch_bounds__(256) void ln_kernel(
    const float* __restrict__ y, const float* __restrict__ g,
    const float* __restrict__ beta, float* __restrict__ out)
{
    __shared__ float red[256];
    const int row = blockIdx.x, t = threadIdx.x;
    float v = y[row * 256 + t];
    red[t] = v; __syncthreads();
    for (int s = 128; s >= 1; s >>= 1) { if (t < s) red[t] += red[t + s]; __syncthreads(); }
    float mu = red[0] * (1.0f / 256.0f);
    __syncthreads();
    float d = v - mu;
    red[t] = d * d; __syncthreads();
    for (int s = 128; s >= 1; s >>= 1) { if (t < s) red[t] += red[t + s]; __syncthreads(); }
    float var = red[0] * (1.0f / 256.0f);
    out[row * 256 + t] = g[t] * d / sqrtf(var + 1e-5f) + beta[t];
}

// ---------------------------------------------------------------------------
// support_g = mean over 5 LN'd support rows; sgn = l2norm(sg0)
// ---------------------------------------------------------------------------
__global__ __launch_bounds__(256) void support_mean_kernel(
    const float* __restrict__ qg2, float* __restrict__ sg0, float* __restrict__ sgn)
{
    __shared__ float red[256];
    const int t = threadIdx.x;
    float s = 0.0f;
    for (int r = 0; r < FEW; ++r) s += qg2[(BB + r) * 256 + t];
    s *= (1.0f / FEW);
    sg0[t] = s;
    red[t] = s * s; __syncthreads();
    for (int k = 128; k >= 1; k >>= 1) { if (t < k) red[t] += red[t + k]; __syncthreads(); }
    sgn[t] = s / fmaxf(sqrtf(red[0]), 1e-12f);
}

__global__ __launch_bounds__(256) void bsum_kernel(
    const float* __restrict__ a, const float* __restrict__ b, float* __restrict__ o)
{
    int i = blockIdx.x * 256 + threadIdx.x;
    o[i] = a[i] + b[i];
}

// gates compact layout: [0:256)=i [256:512)=f [512:768)=g [768:1024)=o
__global__ __launch_bounds__(256) void lstm_step1_kernel(
    const float* __restrict__ gates, const float* __restrict__ qg,
    const float* __restrict__ sg0, float* __restrict__ c1, float* __restrict__ hr)
{
    const int row = blockIdx.x, t = threadIdx.x;
    const float* gr = gates + row * 1024;
    float iv = gr[t], gv = gr[512 + t], ov = gr[768 + t];
    float cv = sigf(iv) * tanhf(gv);          // c0 = 0 => f-term drops
    c1[row * 256 + t] = cv;
    float hf = sigf(ov) * tanhf(cv);
    hr[row * 512 + t]       = qg[row * 256 + t] + hf;  // h1
    hr[row * 512 + 256 + t] = sg0[t];                  // r (attn==1)
}

__global__ __launch_bounds__(256) void lstm_step2_kernel(
    const float* __restrict__ gates, const float* __restrict__ c1,
    const float* __restrict__ qg, const float* __restrict__ sgn,
    float* __restrict__ outv)
{
    __shared__ float red[256];
    __shared__ float red2[256];
    const int row = blockIdx.x, t = threadIdx.x;
    const float* gr = gates + row * 1024;
    float iv = gr[t], fv = gr[256 + t], gv = gr[512 + t], ov = gr[768 + t];
    float cv = sigf(fv) * c1[row * 256 + t] + sigf(iv) * tanhf(gv);
    float h2 = qg[row * 256 + t] + sigf(ov) * tanhf(cv);
    red[t] = h2 * h2; red2[t] = h2 * sgn[t];
    __syncthreads();
    for (int s = 128; s >= 1; s >>= 1) {
        if (t < s) { red[t] += red[t + s]; red2[t] += red2[t + s]; }
        __syncthreads();
    }
    if (t == 0) outv[row] = red2[0] / fmaxf(sqrtf(red[0]), 1e-12f);
}

extern "C" void kernel_launch(void* const* d_in, const int* in_sizes, int n_in,
                              void* d_out, int out_size, void* d_ws, size_t ws_size,
                              hipStream_t stream)
{
    const int*   query    = (const int*)d_in[0];
    const int*   support  = (const int*)d_in[1];
    const int*   q_l_conn = (const int*)d_in[2];
    const int*   q_r_conn = (const int*)d_in[4];
    const int*   s_l_conn = (const int*)d_in[6];
    const int*   s_r_conn = (const int*)d_in[8];
    const float* emb      = (const float*)d_in[10];
    const float* gcn_W    = (const float*)d_in[11];
    const float* gcn_bias = (const float*)d_in[12];
    const float* gcn_b    = (const float*)d_in[13];
    const float* se_w1    = (const float*)d_in[14];
    const float* se_b1    = (const float*)d_in[15];
    const float* se_w2    = (const float*)d_in[16];
    const float* se_b2    = (const float*)d_in[17];
    const float* ln_g     = (const float*)d_in[18];
    const float* ln_b     = (const float*)d_in[19];
    const float* W_ih     = (const float*)d_in[20];
    const float* W_hh     = (const float*)d_in[21];
    const float* b_ih     = (const float*)d_in[22];
    const float* b_hh     = (const float*)d_in[23];
    float* out = (float*)d_out;

    float* ws    = (float*)d_ws;
    float* qn2   = ws;                    // 1088*256
    float* h1q   = qn2   + 1088 * 256;    // 1088*512
    float* yq    = h1q   + 1088 * 512;    // 1088*256
    float* qg2   = yq    + 1088 * 256;    // 1088*256
    float* sg0   = qg2   + 1088 * 256;    // 256
    float* sgn   = sg0   + 256;           // 256
    float* bsum  = sgn   + 256;           // 2048
    float* gates = bsum  + 2048;          // 1024*1024
    float* c1    = gates + 1024 * 1024;   // 1024*256
    float* hr    = c1    + 1024 * 256;    // 1024*512

    // 1. neighbor encoder -> qn2 rows [0,1024)=query, [1024,1029)=support
    neighbor_kernel<<<2 * BB + 2 * FEW, 256, 0, stream>>>(
        query, support, q_l_conn, q_r_conn, s_l_conn, s_r_conn,
        emb, gcn_W, gcn_bias, gcn_b, qn2);

    // 2. bias precompute for LSTM gates
    bsum_kernel<<<8, 256, 0, stream>>>(b_ih, b_hh, bsum);

    // 3. SE MLP (query + support rows folded together, M=1088)
    gemm_nt<true, false, false><<<dim3(8, 17), 256, 0, stream>>>(
        qn2, se_w1, se_b1, nullptr, h1q, 1088, 512, 256);
    gemm_nt<false, true, false><<<dim3(4, 17), 256, 0, stream>>>(
        h1q, se_w2, se_b2, qn2, yq, 1088, 256, 512);
    ln_kernel<<<1029, 256, 0, stream>>>(yq, ln_g, ln_b, qg2);

    // 4. support_g mean + l2norm
    support_mean_kernel<<<1, 256, 0, stream>>>(qg2, sg0, sgn);

    // 5. gates_base = qg @ W_ih'^T + (b_ih+b_hh)   (gate-compacted N=1024)
    gemm_nt<false, false, true><<<dim3(16, 16), 256, 0, stream>>>(
        qg2, W_ih, bsum, nullptr, gates, 1024, 1024, 256);

    // 6. LSTM step 1 (c0=0, h_r0=0 => gates==gates_base)
    lstm_step1_kernel<<<1024, 256, 0, stream>>>(gates, qg2, sg0, c1, hr);

    // 7. gates2 = gates_base + hr @ W_hh'^T   (in-place add)
    gemm_nt<false, true, true><<<dim3(16, 16), 256, 0, stream>>>(
        hr, W_hh, nullptr, gates, gates, 1024, 1024, 512);

    // 8. LSTM step 2 + l2norm + dot(support_gn)
    lstm_step2_kernel<<<1024, 256, 0, stream>>>(gates, c1, qg2, sgn, out);
}